// Round 19
// baseline (400.203 us; speedup 1.0000x reference)
//
#include <hip/hip_runtime.h>
#include <stdint.h>

#define IN_C  256
#define HID   256
#define OUT_C 128
#define SCAN_BS 1024

typedef __bf16 bf16x8 __attribute__((ext_vector_type(8)));
typedef float  f32x4  __attribute__((ext_vector_type(4)));
typedef unsigned short u16x8 __attribute__((ext_vector_type(8)));
typedef unsigned short u16x4 __attribute__((ext_vector_type(4)));
typedef unsigned short u16x2 __attribute__((ext_vector_type(2)));
typedef unsigned int u32;

static __device__ __forceinline__ unsigned short f2b(float f) {
    union { float f; uint32_t u; } v; v.f = f;
    uint32_t r = v.u + 0x7fffu + ((v.u >> 16) & 1u);
    return (unsigned short)(r >> 16);
}
static __device__ __forceinline__ float b2f(unsigned short b) {
    union { uint32_t u; float f; } v; v.u = ((uint32_t)b) << 16;
    return v.f;
}
static __device__ __forceinline__ u32 cvtpk(float lo, float hi) {
    u32 r;
    asm("v_cvt_pk_bf16_f32 %0, %1, %2" : "=v"(r) : "v"(lo), "v"(hi));
    return r;
}

typedef __attribute__((address_space(1))) const u32 gas_u32;
typedef __attribute__((address_space(3))) u32 las_u32;
static __device__ __forceinline__ void gld16(const void* g, void* l) {
    __builtin_amdgcn_global_load_lds((gas_u32*)g, (las_u32*)l, 16, 0, 0);
}
#define SB() __builtin_amdgcn_sched_barrier(0)

// ---------------- init + CSR build ------------------------------------------
__global__ void k_init(const float* __restrict__ W1, const float* __restrict__ W2,
                       unsigned short* __restrict__ W1G, unsigned short* __restrict__ W2T,
                       int* __restrict__ cnt, int n) {
    int i = blockIdx.x * blockDim.x + threadIdx.x;
    if (i < 65536) {
        int gi = i >> 3, j = i & 7;
        int kt = gi >> 10, c = (gi >> 8) & 3, nn = gi & 255;
        W1G[i] = f2b(W1[(size_t)(kt * 32 + c * 8 + j) * HID + nn]);
    }
    if (i < 32768) W2T[i] = f2b(W2[(i & 255) * OUT_C + (i >> 8)]);
    if (i < n) cnt[i] = 0;
}

__global__ void k_count(const int* __restrict__ dst, int* __restrict__ cnt, int e) {
    int i = blockIdx.x * blockDim.x + threadIdx.x;
    if (i < e) atomicAdd(&cnt[dst[i]], 1);
}

__global__ __launch_bounds__(SCAN_BS) void k_scan_block(
    const int* __restrict__ cnt, int* __restrict__ rs, int* __restrict__ bsum, int n) {
    __shared__ int s[SCAN_BS];
    const int tid = threadIdx.x;
    const int i = blockIdx.x * SCAN_BS + tid;
    int v = (i < n) ? cnt[i] + 1 : 0;
    s[tid] = v;
    __syncthreads();
    for (int off = 1; off < SCAN_BS; off <<= 1) {
        int t = (tid >= off) ? s[tid - off] : 0;
        __syncthreads();
        s[tid] += t;
        __syncthreads();
    }
    if (i < n) rs[i] = s[tid] - v;
    if (tid == SCAN_BS - 1) bsum[blockIdx.x] = s[tid];
}

// Merged: each 256-thread block reduces its own bsum prefix (K = blk>>2 <= 97)
// then finalizes rs/cur/dinv + self-loop pair. Replaces the k_scan_sums launch.
__global__ void k_scan_add(int* __restrict__ rs, int* __restrict__ cur,
                           const int* __restrict__ bsum, const int* __restrict__ cnt,
                           float* __restrict__ dinv, int2* __restrict__ csrw, int n) {
    __shared__ int red[256];
    const int tid = threadIdx.x;
    const int K = (int)(blockIdx.x >> 2);   // scan-block index for this 256-window
    int s = 0;
    for (int j = tid; j < K; j += 256) s += bsum[j];
    red[tid] = s;
    __syncthreads();
    #pragma unroll
    for (int off = 128; off > 0; off >>= 1) {
        if (tid < off) red[tid] += red[tid + off];
        __syncthreads();
    }
    const int base = red[0];
    int i = blockIdx.x * 256 + tid;
    if (i < n) {
        int v = rs[i] + base;
        rs[i] = v;
        cur[i] = v + 1;
        float dp1 = (float)(cnt[i] + 1);
        dinv[i] = rsqrtf(dp1);
        csrw[v] = make_int2(i, __float_as_int(1.0f / dp1));
    }
}

__global__ void k_fill(const int* __restrict__ src, const int* __restrict__ dst,
                       const float* __restrict__ dinv,
                       int* __restrict__ cur, int2* __restrict__ csrw, int e) {
    int i = blockIdx.x * blockDim.x + threadIdx.x;
    if (i < e) {
        int s = src[i], d = dst[i];
        int p = atomicAdd(&cur[d], 1);
        csrw[p] = make_int2(s, __float_as_int(dinv[s] * dinv[d]));
    }
}

// ---------------- GEMM1: counted-vmcnt, BM=256 BN=256 BK=32, 1024 thr -------
// 16 waves (4x4), wave tile 64x64. LDS 80KB -> 2 blocks/CU = 32 waves/CU
// (2x the latency hiding of the 512-thr variant at same per-wave stream).
// B triple-buffered (1 gld16/thread/step), A double-buffered reg-cvt path.
// Raw s_barrier + counted vmcnt: B(t+2)'s single load stays in flight.
__global__ __launch_bounds__(1024, 8) void k_gemm1(
    const float* __restrict__ x, const unsigned short* __restrict__ W1G,
    unsigned short* __restrict__ t1, int n) {
    __shared__ __align__(16) unsigned short As[2][8192];   // 2 x 16 KiB
    __shared__ __align__(16) unsigned short Bs[3][8192];   // 3 x 16 KiB
    const int tid  = threadIdx.x;
    const int row0 = blockIdx.x * 256;
    const int wid = tid >> 6, lane = tid & 63;
    const int wm = wid >> 2, wn = wid & 3;
    const int lrow = lane & 15, lgrp = lane >> 4;

    const int ar = tid & 255, ac = tid >> 8;
    int arow = row0 + ar; if (arow > n - 1) arow = n - 1;
    const float* aptr = x + (size_t)arow * IN_C + ac * 8;

    f32x4 acc[4][4];
    #pragma unroll
    for (int i = 0; i < 4; ++i)
        #pragma unroll
        for (int j = 0; j < 4; ++j)
            acc[i][j] = (f32x4){0.f, 0.f, 0.f, 0.f};

    // ---- prologue: A(0) first, then B(0), B(1) ----
    {
        f32x4 a = *(const f32x4*)aptr;
        f32x4 b = *(const f32x4*)(aptr + 4);
        SB();
        gld16(&W1G[(size_t)tid * 8], &Bs[0][tid * 8]);
        gld16(&W1G[(size_t)8192 + tid * 8], &Bs[1][tid * 8]);
        SB();
        union { u32 w[4]; u16x8 v; } pk;
        pk.w[0] = cvtpk(a[0], a[1]); pk.w[1] = cvtpk(a[2], a[3]);
        pk.w[2] = cvtpk(b[0], b[1]); pk.w[3] = cvtpk(b[2], b[3]);
        *(u16x8*)&As[0][ac * 2048 + ar * 8] = pk.v;
        asm volatile("s_waitcnt vmcnt(1) lgkmcnt(0)" ::: "memory"); // B0 done
        SB();
        __builtin_amdgcn_s_barrier();
        SB();
    }

    #pragma unroll
    for (int t = 0; t < 8; ++t) {
        const int cb = t % 3;
        const int ca = t & 1;
        f32x4 pa, pb;
        if (t < 7) {                               // A(t+1) FIRST
            const float* ap = aptr + (t + 1) * 32;
            pa = *(const f32x4*)ap;
            pb = *(const f32x4*)(ap + 4);
        }
        SB();
        if (t < 6)                                 // B(t+2) after A
            gld16(&W1G[(size_t)(t + 2) * 8192 + tid * 8], &Bs[(t + 2) % 3][tid * 8]);
        SB();
        bf16x8 av[4], bv[4];
        #pragma unroll
        for (int mf = 0; mf < 4; ++mf) {
            int r = wm * 64 + mf * 16 + lrow;
            av[mf] = *(const bf16x8*)&As[ca][lgrp * 2048 + r * 8];
        }
        #pragma unroll
        for (int nf = 0; nf < 4; ++nf) {
            int cc = wn * 64 + nf * 16 + lrow;
            bv[nf] = *(const bf16x8*)&Bs[cb][lgrp * 2048 + cc * 8];
        }
        #pragma unroll
        for (int mf = 0; mf < 4; ++mf)
            #pragma unroll
            for (int nf = 0; nf < 4; ++nf)
                acc[mf][nf] = __builtin_amdgcn_mfma_f32_16x16x32_bf16(
                    av[mf], bv[nf], acc[mf][nf], 0, 0, 0);
        SB();
        if (t < 7) {
            union { u32 w[4]; u16x8 v; } pk;
            pk.w[0] = cvtpk(pa[0], pa[1]); pk.w[1] = cvtpk(pa[2], pa[3]);
            pk.w[2] = cvtpk(pb[0], pb[1]); pk.w[3] = cvtpk(pb[2], pb[3]);
            *(u16x8*)&As[(t + 1) & 1][ac * 2048 + ar * 8] = pk.v;
            if (t < 6)
                asm volatile("s_waitcnt vmcnt(1) lgkmcnt(0)" ::: "memory");
            else
                asm volatile("s_waitcnt vmcnt(0) lgkmcnt(0)" ::: "memory");
            SB();
            __builtin_amdgcn_s_barrier();
            SB();
        }
    }

    // ---- epilogue: LDS-staged coalesced C-write (64 rows x 256 cols/chunk)
    __syncthreads();
    unsigned short* Cs = &Bs[0][0];   // need 64*260 = 16640 shorts <= 24576
    #pragma unroll
    for (int mf = 0; mf < 4; ++mf) {
        #pragma unroll
        for (int nf = 0; nf < 4; ++nf)
            #pragma unroll
            for (int j = 0; j < 4; ++j)
                Cs[(wm * 16 + lgrp * 4 + j) * 260 + wn * 64 + nf * 16 + lrow] =
                    f2b(acc[mf][nf][j]);
        __syncthreads();
        #pragma unroll
        for (int it = 0; it < 2; ++it) {
            int chunk = tid + 1024 * it;          // 0..2047
            int lr = chunk >> 5, c8 = chunk & 31;
            u16x8 v = *(const u16x8*)&Cs[lr * 260 + c8 * 8];
            int grow = row0 + (lr >> 4) * 64 + mf * 16 + (lr & 15);
            if (grow < n)
                *(u16x8*)&t1[(size_t)grow * HID + c8 * 8] = v;
        }
        if (mf < 3) __syncthreads();
    }
}

// ---------------- agg1 (R18-frozen): 2-deep pipelined gather ----------------
__global__ __launch_bounds__(256) void k_agg1(
    const unsigned short* __restrict__ t1, const int* __restrict__ rs,
    const int* __restrict__ cnt, const int2* __restrict__ csrw,
    const float* __restrict__ b1, unsigned short* __restrict__ out1, int n) {
    const int w = blockIdx.x * 4 + (threadIdx.x >> 6);
    const int n0 = w * 4;
    if (n0 >= n) return;
    const int lane = threadIdx.x & 63;
    const int ch = lane * 4;
    int beg[4], m[4];
    #pragma unroll
    for (int q = 0; q < 4; ++q) {
        int node = n0 + q;
        bool valid = node < n;
        beg[q] = valid ? rs[node] : 0;
        m[q]   = valid ? cnt[node] + 1 : 0;
    }
    float acc[4][4];
    #pragma unroll
    for (int q = 0; q < 4; ++q)
        #pragma unroll
        for (int k = 0; k < 4; ++k) acc[q][k] = 0.f;
    const int m01 = m[0] > m[1] ? m[0] : m[1];
    const int m23 = m[2] > m[3] ? m[2] : m[3];
    const int mmax = m01 > m23 ? m01 : m23;

    int2 p0[4], p1[4];
    u16x4 r0[4];
    #pragma unroll
    for (int q = 0; q < 4; ++q) p0[q] = csrw[beg[q]];
    #pragma unroll
    for (int q = 0; q < 4; ++q) {
        int idx = (1 < m[q]) ? beg[q] + 1 : beg[q];
        p1[q] = csrw[idx];
    }
    #pragma unroll
    for (int q = 0; q < 4; ++q)
        r0[q] = *(const u16x4*)&t1[(size_t)p0[q].x * HID + ch];

    for (int j = 0; j < mmax; ++j) {
        int2 p2[4];
        u16x4 r1[4];
        #pragma unroll
        for (int q = 0; q < 4; ++q) {
            int jn = j + 2;
            int idx = (jn < m[q]) ? beg[q] + jn : beg[q];
            p2[q] = csrw[idx];
        }
        #pragma unroll
        for (int q = 0; q < 4; ++q)
            r1[q] = *(const u16x4*)&t1[(size_t)p1[q].x * HID + ch];
        #pragma unroll
        for (int q = 0; q < 4; ++q) {
            if (j < m[q]) {
                float wq = __int_as_float(p0[q].y);
                acc[q][0] += b2f(r0[q][0]) * wq; acc[q][1] += b2f(r0[q][1]) * wq;
                acc[q][2] += b2f(r0[q][2]) * wq; acc[q][3] += b2f(r0[q][3]) * wq;
            }
            p0[q] = p1[q]; p1[q] = p2[q]; r0[q] = r1[q];
        }
    }
    float4 bb = *(const float4*)(b1 + ch);
    #pragma unroll
    for (int q = 0; q < 4; ++q) {
        int node = n0 + q;
        if (node < n) {
            u16x4 o;
            o[0] = f2b(fmaxf(acc[q][0] + bb.x, 0.f));
            o[1] = f2b(fmaxf(acc[q][1] + bb.y, 0.f));
            o[2] = f2b(fmaxf(acc[q][2] + bb.z, 0.f));
            o[3] = f2b(fmaxf(acc[q][3] + bb.w, 0.f));
            *(u16x4*)&out1[(size_t)node * HID + ch] = o;
        }
    }
}

// ---------------- GEMM2 (R15-frozen) ----------------------------------------
__global__ __launch_bounds__(256) void k_gemm2(
    const unsigned short* __restrict__ out1, const unsigned short* __restrict__ W2T,
    unsigned short* __restrict__ t2, int n) {
    __shared__ __align__(16) unsigned short As[128 * 64];
    __shared__ __align__(16) unsigned short Bs[128 * 64];
    const int tid  = threadIdx.x;
    const int row0 = blockIdx.x * 128;
    const int wid = tid >> 6, lane = tid & 63;
    const int wm = wid >> 1, wn = wid & 1;
    const int lrow = lane & 15, lgrp = lane >> 4;

    f32x4 acc[4][4];
    #pragma unroll
    for (int i = 0; i < 4; ++i)
        #pragma unroll
        for (int j = 0; j < 4; ++j)
            acc[i][j] = (f32x4){0.f, 0.f, 0.f, 0.f};

    for (int kt = 0; kt < 4; ++kt) {
        #pragma unroll
        for (int i = 0; i < 4; ++i) {
            int chunk = tid + 256 * i;
            int r = chunk >> 3, c = chunk & 7;
            int grow = row0 + r; if (grow > n - 1) grow = n - 1;
            gld16(&out1[(size_t)grow * HID + kt * 64 + ((c ^ (r & 7)) * 8)],
                  &As[chunk * 8]);
        }
        #pragma unroll
        for (int i = 0; i < 4; ++i) {
            int chunk = tid + 256 * i;
            int nn = chunk >> 3, c = chunk & 7;
            gld16(&W2T[(size_t)nn * 256 + kt * 64 + ((c ^ (nn & 7)) * 8)],
                  &Bs[chunk * 8]);
        }
        __syncthreads();
        #pragma unroll
        for (int kk = 0; kk < 2; ++kk) {
            const int cfrag = kk * 4 + lgrp;
            bf16x8 av[4], bv[4];
            #pragma unroll
            for (int mf = 0; mf < 4; ++mf) {
                int r = wm * 64 + mf * 16 + lrow;
                av[mf] = *(const bf16x8*)&As[r * 64 + ((cfrag ^ (r & 7)) * 8)];
            }
            #pragma unroll
            for (int nf = 0; nf < 4; ++nf) {
                int cc = wn * 64 + nf * 16 + lrow;
                bv[nf] = *(const bf16x8*)&Bs[cc * 64 + ((cfrag ^ (cc & 7)) * 8)];
            }
            #pragma unroll
            for (int mf = 0; mf < 4; ++mf)
                #pragma unroll
                for (int nf = 0; nf < 4; ++nf)
                    acc[mf][nf] = __builtin_amdgcn_mfma_f32_16x16x32_bf16(
                        av[mf], bv[nf], acc[mf][nf], 0, 0, 0);
        }
        __syncthreads();
    }

    unsigned short* Cs = &Bs[0];
    #pragma unroll
    for (int mf = 0; mf < 4; ++mf) {
        #pragma unroll
        for (int nf = 0; nf < 4; ++nf)
            #pragma unroll
            for (int j = 0; j < 4; ++j)
                Cs[(wm * 16 + lgrp * 4 + j) * 132 + wn * 64 + nf * 16 + lrow] =
                    f2b(acc[mf][nf][j]);
        __syncthreads();
        #pragma unroll
        for (int it = 0; it < 2; ++it) {
            int chunk = tid + 256 * it;
            int lr = chunk >> 4, c8 = chunk & 15;
            u16x8 v = *(const u16x8*)&Cs[lr * 132 + c8 * 8];
            int grow = row0 + (lr >> 4) * 64 + mf * 16 + (lr & 15);
            if (grow < n)
                *(u16x8*)&t2[(size_t)grow * OUT_C + c8 * 8] = v;
        }
        if (mf < 3) __syncthreads();
    }
}

// ---------------- agg2 (R18-frozen): 2-deep pipelined gather ----------------
__global__ __launch_bounds__(256) void k_agg2(
    const unsigned short* __restrict__ t2, const int* __restrict__ rs,
    const int* __restrict__ cnt, const int2* __restrict__ csrw,
    const float* __restrict__ b2, float* __restrict__ out, int n) {
    const int w = blockIdx.x * 4 + (threadIdx.x >> 6);
    const int n0 = w * 4;
    if (n0 >= n) return;
    const int lane = threadIdx.x & 63;
    const int ch = lane * 2;
    int beg[4], m[4];
    #pragma unroll
    for (int q = 0; q < 4; ++q) {
        int node = n0 + q;
        bool valid = node < n;
        beg[q] = valid ? rs[node] : 0;
        m[q]   = valid ? cnt[node] + 1 : 0;
    }
    float acc[4][2];
    #pragma unroll
    for (int q = 0; q < 4; ++q) { acc[q][0] = 0.f; acc[q][1] = 0.f; }
    const int m01 = m[0] > m[1] ? m[0] : m[1];
    const int m23 = m[2] > m[3] ? m[2] : m[3];
    const int mmax = m01 > m23 ? m01 : m23;

    int2 p0[4], p1[4];
    u16x2 r0[4];
    #pragma unroll
    for (int q = 0; q < 4; ++q) p0[q] = csrw[beg[q]];
    #pragma unroll
    for (int q = 0; q < 4; ++q) {
        int idx = (1 < m[q]) ? beg[q] + 1 : beg[q];
        p1[q] = csrw[idx];
    }
    #pragma unroll
    for (int q = 0; q < 4; ++q)
        r0[q] = *(const u16x2*)&t2[(size_t)p0[q].x * OUT_C + ch];

    for (int j = 0; j < mmax; ++j) {
        int2 p2[4];
        u16x2 r1[4];
        #pragma unroll
        for (int q = 0; q < 4; ++q) {
            int jn = j + 2;
            int idx = (jn < m[q]) ? beg[q] + jn : beg[q];
            p2[q] = csrw[idx];
        }
        #pragma unroll
        for (int q = 0; q < 4; ++q)
            r1[q] = *(const u16x2*)&t2[(size_t)p1[q].x * OUT_C + ch];
        #pragma unroll
        for (int q = 0; q < 4; ++q) {
            if (j < m[q]) {
                float wq = __int_as_float(p0[q].y);
                acc[q][0] += b2f(r0[q][0]) * wq; acc[q][1] += b2f(r0[q][1]) * wq;
            }
            p0[q] = p1[q]; p1[q] = p2[q]; r0[q] = r1[q];
        }
    }
    float2 bb = *(const float2*)(b2 + ch);
    #pragma unroll
    for (int q = 0; q < 4; ++q) {
        int node = n0 + q;
        if (node < n)
            *(float2*)&out[(size_t)node * OUT_C + ch] =
                make_float2(acc[q][0] + bb.x, acc[q][1] + bb.y);
    }
}

extern "C" void kernel_launch(void* const* d_in, const int* in_sizes, int n_in,
                              void* d_out, int out_size, void* d_ws, size_t ws_size,
                              hipStream_t stream) {
    const float* x  = (const float*)d_in[0];
    const int*   ei = (const int*)d_in[1];
    const float* W1 = (const float*)d_in[2];
    const float* b1 = (const float*)d_in[3];
    const float* W2 = (const float*)d_in[4];
    const float* b2 = (const float*)d_in[5];
    float* out = (float*)d_out;

    const int n = in_sizes[0] / IN_C;   // 100000
    const int e = in_sizes[1] / 2;      // 300000
    const int* src = ei;
    const int* dst = ei + e;

    int*   cnt  = (int*)d_ws;                       // [n]
    int*   rs   = cnt + n;                          // [n]
    int*   cur  = rs + n;                           // [n]
    int*   bsum = cur + n;                          // [128]
    float* dinv = (float*)(bsum + 128);             // [n]
    int2*  csrw = (int2*)(dinv + n);                // [e+n]
    unsigned short* W1G = (unsigned short*)(csrw + (size_t)e + n);  // [256*256]
    unsigned short* W2T = W1G + 65536;                              // [128*256]
    unsigned short* t1  = W2T + 32768;                              // [n*HID]
    unsigned short* out1 = t1 + (size_t)n * HID;                    // [n*HID]
    unsigned short* t2  = t1;                                       // alias

    const int nb = (n + SCAN_BS - 1) / SCAN_BS;

    k_init<<<(n + 255) / 256, 256, 0, stream>>>(W1, W2, W1G, W2T, cnt, n);
    k_count<<<(e + 255) / 256, 256, 0, stream>>>(dst, cnt, e);
    k_scan_block<<<nb, SCAN_BS, 0, stream>>>(cnt, rs, bsum, n);
    k_scan_add<<<(n + 255) / 256, 256, 0, stream>>>(rs, cur, bsum, cnt, dinv, csrw, n);
    k_fill<<<(e + 255) / 256, 256, 0, stream>>>(src, dst, dinv, cur, csrw, e);

    const int mb1 = (n + 255) / 256;   // 391
    k_gemm1<<<mb1, 1024, 0, stream>>>(x, W1G, t1, n);
    const int aggblk = (n + 15) / 16;
    k_agg1<<<aggblk, 256, 0, stream>>>(t1, rs, cnt, csrw, b1, out1, n);
    const int mb2 = (n + 127) / 128;   // 782
    k_gemm2<<<mb2, 256, 0, stream>>>(out1, W2T, t2, n);
    k_agg2<<<aggblk, 256, 0, stream>>>(t2, rs, cnt, csrw, b2, out, n);
}

// Round 20
// 191.812 us; speedup vs baseline: 2.0864x; 2.0864x over previous
//
#include <hip/hip_runtime.h>
#include <stdint.h>

#define IN_C  256
#define HID   256
#define OUT_C 128
#define SCAN_BS 1024

typedef __bf16 bf16x8 __attribute__((ext_vector_type(8)));
typedef float  f32x4  __attribute__((ext_vector_type(4)));
typedef unsigned short u16x8 __attribute__((ext_vector_type(8)));
typedef unsigned short u16x4 __attribute__((ext_vector_type(4)));
typedef unsigned short u16x2 __attribute__((ext_vector_type(2)));
typedef unsigned int u32;

static __device__ __forceinline__ unsigned short f2b(float f) {
    union { float f; uint32_t u; } v; v.f = f;
    uint32_t r = v.u + 0x7fffu + ((v.u >> 16) & 1u);
    return (unsigned short)(r >> 16);
}
static __device__ __forceinline__ float b2f(unsigned short b) {
    union { uint32_t u; float f; } v; v.u = ((uint32_t)b) << 16;
    return v.f;
}
static __device__ __forceinline__ u32 cvtpk(float lo, float hi) {
    u32 r;
    asm("v_cvt_pk_bf16_f32 %0, %1, %2" : "=v"(r) : "v"(lo), "v"(hi));
    return r;
}

typedef __attribute__((address_space(1))) const u32 gas_u32;
typedef __attribute__((address_space(3))) u32 las_u32;
static __device__ __forceinline__ void gld16(const void* g, void* l) {
    __builtin_amdgcn_global_load_lds((gas_u32*)g, (las_u32*)l, 16, 0, 0);
}
#define SB() __builtin_amdgcn_sched_barrier(0)

// ---------------- init + CSR build (R12/R15-proven) -------------------------
__global__ void k_init(const float* __restrict__ W1, const float* __restrict__ W2,
                       unsigned short* __restrict__ W1G, unsigned short* __restrict__ W2T,
                       int* __restrict__ cnt, int n) {
    int i = blockIdx.x * blockDim.x + threadIdx.x;
    if (i < 65536) {
        int gi = i >> 3, j = i & 7;
        int kt = gi >> 10, c = (gi >> 8) & 3, nn = gi & 255;
        W1G[i] = f2b(W1[(size_t)(kt * 32 + c * 8 + j) * HID + nn]);
    }
    if (i < 32768) W2T[i] = f2b(W2[(i & 255) * OUT_C + (i >> 8)]);
    if (i < n) cnt[i] = 0;
}

__global__ void k_count(const int* __restrict__ dst, int* __restrict__ cnt, int e) {
    int i = blockIdx.x * blockDim.x + threadIdx.x;
    if (i < e) atomicAdd(&cnt[dst[i]], 1);
}

__global__ __launch_bounds__(SCAN_BS) void k_scan_block(
    const int* __restrict__ cnt, int* __restrict__ rs, int* __restrict__ bsum, int n) {
    __shared__ int s[SCAN_BS];
    const int tid = threadIdx.x;
    const int i = blockIdx.x * SCAN_BS + tid;
    int v = (i < n) ? cnt[i] + 1 : 0;
    s[tid] = v;
    __syncthreads();
    for (int off = 1; off < SCAN_BS; off <<= 1) {
        int t = (tid >= off) ? s[tid - off] : 0;
        __syncthreads();
        s[tid] += t;
        __syncthreads();
    }
    if (i < n) rs[i] = s[tid] - v;
    if (tid == SCAN_BS - 1) bsum[blockIdx.x] = s[tid];
}

__global__ void k_scan_sums(int* __restrict__ bsum, int nb) {
    __shared__ int s[128];
    const int tid = threadIdx.x;
    int v = (tid < nb) ? bsum[tid] : 0;
    s[tid] = v;
    __syncthreads();
    for (int off = 1; off < 128; off <<= 1) {
        int t = (tid >= off) ? s[tid - off] : 0;
        __syncthreads();
        s[tid] += t;
        __syncthreads();
    }
    if (tid < nb) bsum[tid] = s[tid] - v;
}

__global__ void k_scan_add(int* __restrict__ rs, int* __restrict__ cur,
                           const int* __restrict__ bsum, const int* __restrict__ cnt,
                           float* __restrict__ dinv, int2* __restrict__ csrw, int n) {
    int i = blockIdx.x * blockDim.x + threadIdx.x;
    if (i < n) {
        int v = rs[i] + bsum[i >> 10];
        rs[i] = v;
        cur[i] = v + 1;
        float dp1 = (float)(cnt[i] + 1);
        dinv[i] = rsqrtf(dp1);
        csrw[v] = make_int2(i, __float_as_int(1.0f / dp1));
    }
}

__global__ void k_fill(const int* __restrict__ src, const int* __restrict__ dst,
                       const float* __restrict__ dinv,
                       int* __restrict__ cur, int2* __restrict__ csrw, int e) {
    int i = blockIdx.x * blockDim.x + threadIdx.x;
    if (i < e) {
        int s = src[i], d = dst[i];
        int p = atomicAdd(&cur[d], 1);
        csrw[p] = make_int2(s, __float_as_int(dinv[s] * dinv[d]));
    }
}

// ---------------- GEMM1 (R16-frozen): counted-vmcnt pipelined ---------------
__global__ __launch_bounds__(512) void k_gemm1(
    const float* __restrict__ x, const unsigned short* __restrict__ W1G,
    unsigned short* __restrict__ t1, int n) {
    __shared__ __align__(16) unsigned short As[2][4096];
    __shared__ __align__(16) unsigned short Bs[3][8192];
    const int tid  = threadIdx.x;
    const int row0 = blockIdx.x * 128;
    const int wid = tid >> 6, lane = tid & 63;
    const int wm = wid >> 2, wn = wid & 3;
    const int lrow = lane & 15, lgrp = lane >> 4;

    const int ar = tid & 127, ac = tid >> 7;
    int arow = row0 + ar; if (arow > n - 1) arow = n - 1;
    const float* aptr = x + (size_t)arow * IN_C + ac * 8;

    f32x4 acc[4][4];
    #pragma unroll
    for (int i = 0; i < 4; ++i)
        #pragma unroll
        for (int j = 0; j < 4; ++j)
            acc[i][j] = (f32x4){0.f, 0.f, 0.f, 0.f};

    {
        f32x4 a = *(const f32x4*)aptr;
        f32x4 b = *(const f32x4*)(aptr + 4);
        SB();
        #pragma unroll
        for (int i = 0; i < 2; ++i) {
            int chunk = tid + 512 * i;
            gld16(&W1G[(size_t)chunk * 8], &Bs[0][chunk * 8]);
        }
        #pragma unroll
        for (int i = 0; i < 2; ++i) {
            int chunk = tid + 512 * i;
            gld16(&W1G[(size_t)8192 + chunk * 8], &Bs[1][chunk * 8]);
        }
        SB();
        union { u32 w[4]; u16x8 v; } pk;
        pk.w[0] = cvtpk(a[0], a[1]); pk.w[1] = cvtpk(a[2], a[3]);
        pk.w[2] = cvtpk(b[0], b[1]); pk.w[3] = cvtpk(b[2], b[3]);
        *(u16x8*)&As[0][ac * 1024 + ar * 8] = pk.v;
        asm volatile("s_waitcnt vmcnt(2) lgkmcnt(0)" ::: "memory");
        SB();
        __builtin_amdgcn_s_barrier();
        SB();
    }

    #pragma unroll
    for (int t = 0; t < 8; ++t) {
        const int cb = t % 3;
        const int ca = t & 1;
        f32x4 pa, pb;
        if (t < 7) {
            const float* ap = aptr + (t + 1) * 32;
            pa = *(const f32x4*)ap;
            pb = *(const f32x4*)(ap + 4);
        }
        SB();
        if (t < 6) {
            const int nb3 = (t + 2) % 3;
            #pragma unroll
            for (int i = 0; i < 2; ++i) {
                int chunk = tid + 512 * i;
                gld16(&W1G[(size_t)(t + 2) * 8192 + chunk * 8], &Bs[nb3][chunk * 8]);
            }
        }
        SB();
        bf16x8 av[4], bv[4];
        #pragma unroll
        for (int mf = 0; mf < 4; ++mf) {
            int r = wm * 64 + mf * 16 + lrow;
            av[mf] = *(const bf16x8*)&As[ca][lgrp * 1024 + r * 8];
        }
        #pragma unroll
        for (int nf = 0; nf < 4; ++nf) {
            int cc = wn * 64 + nf * 16 + lrow;
            bv[nf] = *(const bf16x8*)&Bs[cb][lgrp * 2048 + cc * 8];
        }
        #pragma unroll
        for (int mf = 0; mf < 4; ++mf)
            #pragma unroll
            for (int nf = 0; nf < 4; ++nf)
                acc[mf][nf] = __builtin_amdgcn_mfma_f32_16x16x32_bf16(
                    av[mf], bv[nf], acc[mf][nf], 0, 0, 0);
        SB();
        if (t < 7) {
            union { u32 w[4]; u16x8 v; } pk;
            pk.w[0] = cvtpk(pa[0], pa[1]); pk.w[1] = cvtpk(pa[2], pa[3]);
            pk.w[2] = cvtpk(pb[0], pb[1]); pk.w[3] = cvtpk(pb[2], pb[3]);
            *(u16x8*)&As[(t + 1) & 1][ac * 1024 + ar * 8] = pk.v;
            if (t < 6)
                asm volatile("s_waitcnt vmcnt(2) lgkmcnt(0)" ::: "memory");
            else
                asm volatile("s_waitcnt vmcnt(0) lgkmcnt(0)" ::: "memory");
            SB();
            __builtin_amdgcn_s_barrier();
            SB();
        }
    }

    __syncthreads();
    unsigned short* Cs = &Bs[0][0];
    #pragma unroll
    for (int mf = 0; mf < 4; ++mf) {
        #pragma unroll
        for (int nf = 0; nf < 4; ++nf)
            #pragma unroll
            for (int j = 0; j < 4; ++j)
                Cs[(wm * 16 + lgrp * 4 + j) * 260 + wn * 64 + nf * 16 + lrow] =
                    f2b(acc[mf][nf][j]);
        __syncthreads();
        #pragma unroll
        for (int it = 0; it < 2; ++it) {
            int chunk = tid + 512 * it;
            int lr = chunk >> 5, c8 = chunk & 31;
            u16x8 v = *(const u16x8*)&Cs[lr * 260 + c8 * 8];
            int grow = row0 + (lr >> 4) * 64 + mf * 16 + (lr & 15);
            if (grow < n)
                *(u16x8*)&t1[(size_t)grow * HID + c8 * 8] = v;
        }
        if (mf < 3) __syncthreads();
    }
}

// ---------------- agg1 (R18): 2-deep pipelined gather -----------------------
__global__ __launch_bounds__(256) void k_agg1(
    const unsigned short* __restrict__ t1, const int* __restrict__ rs,
    const int* __restrict__ cnt, const int2* __restrict__ csrw,
    const float* __restrict__ b1, unsigned short* __restrict__ out1, int n) {
    const int w = blockIdx.x * 4 + (threadIdx.x >> 6);
    const int n0 = w * 4;
    if (n0 >= n) return;
    const int lane = threadIdx.x & 63;
    const int ch = lane * 4;
    int beg[4], m[4];
    #pragma unroll
    for (int q = 0; q < 4; ++q) {
        int node = n0 + q;
        bool valid = node < n;
        beg[q] = valid ? rs[node] : 0;
        m[q]   = valid ? cnt[node] + 1 : 0;
    }
    float acc[4][4];
    #pragma unroll
    for (int q = 0; q < 4; ++q)
        #pragma unroll
        for (int k = 0; k < 4; ++k) acc[q][k] = 0.f;
    const int m01 = m[0] > m[1] ? m[0] : m[1];
    const int m23 = m[2] > m[3] ? m[2] : m[3];
    const int mmax = m01 > m23 ? m01 : m23;

    int2 p0[4], p1[4];
    u16x4 r0[4];
    #pragma unroll
    for (int q = 0; q < 4; ++q) p0[q] = csrw[beg[q]];
    #pragma unroll
    for (int q = 0; q < 4; ++q) {
        int idx = (1 < m[q]) ? beg[q] + 1 : beg[q];
        p1[q] = csrw[idx];
    }
    #pragma unroll
    for (int q = 0; q < 4; ++q)
        r0[q] = *(const u16x4*)&t1[(size_t)p0[q].x * HID + ch];

    for (int j = 0; j < mmax; ++j) {
        int2 p2[4];
        u16x4 r1[4];
        #pragma unroll
        for (int q = 0; q < 4; ++q) {
            int jn = j + 2;
            int idx = (jn < m[q]) ? beg[q] + jn : beg[q];
            p2[q] = csrw[idx];
        }
        #pragma unroll
        for (int q = 0; q < 4; ++q)
            r1[q] = *(const u16x4*)&t1[(size_t)p1[q].x * HID + ch];
        #pragma unroll
        for (int q = 0; q < 4; ++q) {
            if (j < m[q]) {
                float wq = __int_as_float(p0[q].y);
                acc[q][0] += b2f(r0[q][0]) * wq; acc[q][1] += b2f(r0[q][1]) * wq;
                acc[q][2] += b2f(r0[q][2]) * wq; acc[q][3] += b2f(r0[q][3]) * wq;
            }
            p0[q] = p1[q]; p1[q] = p2[q]; r0[q] = r1[q];
        }
    }
    float4 bb = *(const float4*)(b1 + ch);
    #pragma unroll
    for (int q = 0; q < 4; ++q) {
        int node = n0 + q;
        if (node < n) {
            u16x4 o;
            o[0] = f2b(fmaxf(acc[q][0] + bb.x, 0.f));
            o[1] = f2b(fmaxf(acc[q][1] + bb.y, 0.f));
            o[2] = f2b(fmaxf(acc[q][2] + bb.z, 0.f));
            o[3] = f2b(fmaxf(acc[q][3] + bb.w, 0.f));
            *(u16x4*)&out1[(size_t)node * HID + ch] = o;
        }
    }
}

// ---------------- GEMM2 (R15-frozen) ----------------------------------------
__global__ __launch_bounds__(256) void k_gemm2(
    const unsigned short* __restrict__ out1, const unsigned short* __restrict__ W2T,
    unsigned short* __restrict__ t2, int n) {
    __shared__ __align__(16) unsigned short As[128 * 64];
    __shared__ __align__(16) unsigned short Bs[128 * 64];
    const int tid  = threadIdx.x;
    const int row0 = blockIdx.x * 128;
    const int wid = tid >> 6, lane = tid & 63;
    const int wm = wid >> 1, wn = wid & 1;
    const int lrow = lane & 15, lgrp = lane >> 4;

    f32x4 acc[4][4];
    #pragma unroll
    for (int i = 0; i < 4; ++i)
        #pragma unroll
        for (int j = 0; j < 4; ++j)
            acc[i][j] = (f32x4){0.f, 0.f, 0.f, 0.f};

    for (int kt = 0; kt < 4; ++kt) {
        #pragma unroll
        for (int i = 0; i < 4; ++i) {
            int chunk = tid + 256 * i;
            int r = chunk >> 3, c = chunk & 7;
            int grow = row0 + r; if (grow > n - 1) grow = n - 1;
            gld16(&out1[(size_t)grow * HID + kt * 64 + ((c ^ (r & 7)) * 8)],
                  &As[chunk * 8]);
        }
        #pragma unroll
        for (int i = 0; i < 4; ++i) {
            int chunk = tid + 256 * i;
            int nn = chunk >> 3, c = chunk & 7;
            gld16(&W2T[(size_t)nn * 256 + kt * 64 + ((c ^ (nn & 7)) * 8)],
                  &Bs[chunk * 8]);
        }
        __syncthreads();
        #pragma unroll
        for (int kk = 0; kk < 2; ++kk) {
            const int cfrag = kk * 4 + lgrp;
            bf16x8 av[4], bv[4];
            #pragma unroll
            for (int mf = 0; mf < 4; ++mf) {
                int r = wm * 64 + mf * 16 + lrow;
                av[mf] = *(const bf16x8*)&As[r * 64 + ((cfrag ^ (r & 7)) * 8)];
            }
            #pragma unroll
            for (int nf = 0; nf < 4; ++nf) {
                int cc = wn * 64 + nf * 16 + lrow;
                bv[nf] = *(const bf16x8*)&Bs[cc * 64 + ((cfrag ^ (cc & 7)) * 8)];
            }
            #pragma unroll
            for (int mf = 0; mf < 4; ++mf)
                #pragma unroll
                for (int nf = 0; nf < 4; ++nf)
                    acc[mf][nf] = __builtin_amdgcn_mfma_f32_16x16x32_bf16(
                        av[mf], bv[nf], acc[mf][nf], 0, 0, 0);
        }
        __syncthreads();
    }

    unsigned short* Cs = &Bs[0];
    #pragma unroll
    for (int mf = 0; mf < 4; ++mf) {
        #pragma unroll
        for (int nf = 0; nf < 4; ++nf)
            #pragma unroll
            for (int j = 0; j < 4; ++j)
                Cs[(wm * 16 + lgrp * 4 + j) * 132 + wn * 64 + nf * 16 + lrow] =
                    f2b(acc[mf][nf][j]);
        __syncthreads();
        #pragma unroll
        for (int it = 0; it < 2; ++it) {
            int chunk = tid + 256 * it;
            int lr = chunk >> 4, c8 = chunk & 15;
            u16x8 v = *(const u16x8*)&Cs[lr * 132 + c8 * 8];
            int grow = row0 + (lr >> 4) * 64 + mf * 16 + (lr & 15);
            if (grow < n)
                *(u16x8*)&t2[(size_t)grow * OUT_C + c8 * 8] = v;
        }
        if (mf < 3) __syncthreads();
    }
}

// ---------------- agg2 (R18): 2-deep pipelined gather -----------------------
__global__ __launch_bounds__(256) void k_agg2(
    const unsigned short* __restrict__ t2, const int* __restrict__ rs,
    const int* __restrict__ cnt, const int2* __restrict__ csrw,
    const float* __restrict__ b2, float* __restrict__ out, int n) {
    const int w = blockIdx.x * 4 + (threadIdx.x >> 6);
    const int n0 = w * 4;
    if (n0 >= n) return;
    const int lane = threadIdx.x & 63;
    const int ch = lane * 2;
    int beg[4], m[4];
    #pragma unroll
    for (int q = 0; q < 4; ++q) {
        int node = n0 + q;
        bool valid = node < n;
        beg[q] = valid ? rs[node] : 0;
        m[q]   = valid ? cnt[node] + 1 : 0;
    }
    float acc[4][2];
    #pragma unroll
    for (int q = 0; q < 4; ++q) { acc[q][0] = 0.f; acc[q][1] = 0.f; }
    const int m01 = m[0] > m[1] ? m[0] : m[1];
    const int m23 = m[2] > m[3] ? m[2] : m[3];
    const int mmax = m01 > m23 ? m01 : m23;

    int2 p0[4], p1[4];
    u16x2 r0[4];
    #pragma unroll
    for (int q = 0; q < 4; ++q) p0[q] = csrw[beg[q]];
    #pragma unroll
    for (int q = 0; q < 4; ++q) {
        int idx = (1 < m[q]) ? beg[q] + 1 : beg[q];
        p1[q] = csrw[idx];
    }
    #pragma unroll
    for (int q = 0; q < 4; ++q)
        r0[q] = *(const u16x2*)&t2[(size_t)p0[q].x * OUT_C + ch];

    for (int j = 0; j < mmax; ++j) {
        int2 p2[4];
        u16x2 r1[4];
        #pragma unroll
        for (int q = 0; q < 4; ++q) {
            int jn = j + 2;
            int idx = (jn < m[q]) ? beg[q] + jn : beg[q];
            p2[q] = csrw[idx];
        }
        #pragma unroll
        for (int q = 0; q < 4; ++q)
            r1[q] = *(const u16x2*)&t2[(size_t)p1[q].x * OUT_C + ch];
        #pragma unroll
        for (int q = 0; q < 4; ++q) {
            if (j < m[q]) {
                float wq = __int_as_float(p0[q].y);
                acc[q][0] += b2f(r0[q][0]) * wq; acc[q][1] += b2f(r0[q][1]) * wq;
            }
            p0[q] = p1[q]; p1[q] = p2[q]; r0[q] = r1[q];
        }
    }
    float2 bb = *(const float2*)(b2 + ch);
    #pragma unroll
    for (int q = 0; q < 4; ++q) {
        int node = n0 + q;
        if (node < n)
            *(float2*)&out[(size_t)node * OUT_C + ch] =
                make_float2(acc[q][0] + bb.x, acc[q][1] + bb.y);
    }
}

extern "C" void kernel_launch(void* const* d_in, const int* in_sizes, int n_in,
                              void* d_out, int out_size, void* d_ws, size_t ws_size,
                              hipStream_t stream) {
    const float* x  = (const float*)d_in[0];
    const int*   ei = (const int*)d_in[1];
    const float* W1 = (const float*)d_in[2];
    const float* b1 = (const float*)d_in[3];
    const float* W2 = (const float*)d_in[4];
    const float* b2 = (const float*)d_in[5];
    float* out = (float*)d_out;

    const int n = in_sizes[0] / IN_C;   // 100000
    const int e = in_sizes[1] / 2;      // 300000
    const int* src = ei;
    const int* dst = ei + e;

    int*   cnt  = (int*)d_ws;                       // [n]
    int*   rs   = cnt + n;                          // [n]
    int*   cur  = rs + n;                           // [n]
    int*   bsum = cur + n;                          // [128]
    float* dinv = (float*)(bsum + 128);             // [n]
    int2*  csrw = (int2*)(dinv + n);                // [e+n]
    unsigned short* W1G = (unsigned short*)(csrw + (size_t)e + n);  // [256*256]
    unsigned short* W2T = W1G + 65536;                              // [128*256]
    unsigned short* t1  = W2T + 32768;                              // [n*HID]
    unsigned short* out1 = t1 + (size_t)n * HID;                    // [n*HID]
    unsigned short* t2  = t1;                                       // alias

    const int nb = (n + SCAN_BS - 1) / SCAN_BS;

    k_init<<<(n + 255) / 256, 256, 0, stream>>>(W1, W2, W1G, W2T, cnt, n);
    k_count<<<(e + 255) / 256, 256, 0, stream>>>(dst, cnt, e);
    k_scan_block<<<nb, SCAN_BS, 0, stream>>>(cnt, rs, bsum, n);
    k_scan_sums<<<1, 128, 0, stream>>>(bsum, nb);
    k_scan_add<<<(n + 255) / 256, 256, 0, stream>>>(rs, cur, bsum, cnt, dinv, csrw, n);
    k_fill<<<(e + 255) / 256, 256, 0, stream>>>(src, dst, dinv, cur, csrw, e);

    const int mb = (n + 127) / 128;   // 782
    k_gemm1<<<mb, 512, 0, stream>>>(x, W1G, t1, n);
    const int aggblk = (n + 15) / 16;
    k_agg1<<<aggblk, 256, 0, stream>>>(t1, rs, cnt, csrw, b1, out1, n);
    k_gemm2<<<mb, 256, 0, stream>>>(out1, W2T, t2, n);
    k_agg2<<<aggblk, 256, 0, stream>>>(t2, rs, cnt, csrw, b2, out, n);
}